// Round 1
// baseline (407.872 us; speedup 1.0000x reference)
//
#include <hip/hip_runtime.h>

#define SEQ   2048
#define BATCH 4
#define NH    16
#define DM    1024
#define MTOT  (BATCH*SEQ)   // 8192

typedef unsigned short u16;
typedef unsigned int   u32;
typedef __attribute__((ext_vector_type(8))) __bf16 bf16x8;
typedef __attribute__((ext_vector_type(4))) float  f32x4;
typedef __attribute__((address_space(1))) u32 as1_u32;
typedef __attribute__((address_space(3))) u32 as3_u32;

__device__ __forceinline__ u16 f2bf(float f) {
  union { float f; u32 u; } c; c.f = f;
  return (u16)((c.u + 0x7fffu + ((c.u >> 16) & 1u)) >> 16);
}

__global__ void cast_bf16_k(const float* __restrict__ in, u16* __restrict__ out, int n4) {
  int i = blockIdx.x * blockDim.x + threadIdx.x;
  if (i < n4) {
    float4 v = reinterpret_cast<const float4*>(in)[i];
    ushort4 o;
    o.x = f2bf(v.x); o.y = f2bf(v.y); o.z = f2bf(v.z); o.w = f2bf(v.w);
    reinterpret_cast<ushort4*>(out)[i] = o;
  }
}

__global__ void rope_tab_k(const int* __restrict__ pos, float2* __restrict__ tab) {
  int i = blockIdx.x * blockDim.x + threadIdx.x;  // s*32 + j
  if (i < SEQ * 32) {
    int s = i >> 5, j = i & 31;
    float p = (float)pos[s];
    float fr = powf(10000.f, -(float)j / 32.f);
    float a = p * fr;
    tab[i] = make_float2(cosf(a), sinf(a));
  }
}

// C = A @ Bt^T.  A: [M,1024] bf16 row-major. Bt: [1024,1024] bf16 row-major ([N][K]).
// EPI 0: fp32 store to outF. EPI 1: z=0/1 -> RoPE -> Qh/Kh [B,H,S,64]; z=2 -> Vt [B,H,64,S].
template<int EPI>
__global__ __launch_bounds__(256)
void gemm_bt(const u16* __restrict__ A,
             const u16* __restrict__ B0, const u16* __restrict__ B1, const u16* __restrict__ B2,
             float* __restrict__ outF,
             u16* __restrict__ Qh, u16* __restrict__ Kh, u16* __restrict__ Vt,
             const float2* __restrict__ tab) {
  const int K = DM, N = DM;
  __shared__ u16 lsA[128 * 32];
  __shared__ u16 lsB[128 * 32];
  const int t = threadIdx.x;
  const int lane = t & 63;
  const int wid = t >> 6;
  const int wr = wid >> 1, wc = wid & 1;
  const int m0 = blockIdx.y * 128, n0 = blockIdx.x * 128;
  const int z = blockIdx.z;
  const u16* Bt = (z == 0) ? B0 : (z == 1 ? B1 : B2);

  f32x4 acc[4][4] = {};

  const int srow = t >> 2;
  const int scol = (t & 3) * 8;
  const u16* gA = A + (size_t)(m0 + srow) * K + scol;
  const u16* gB = Bt + (size_t)(n0 + srow) * K + scol;
  const u32 lo = (u32)t * 16u;

  for (int kt = 0; kt < K; kt += 32) {
    __builtin_amdgcn_global_load_lds((const as1_u32*)(gA + kt),
                                     (as3_u32*)((char*)lsA + lo), 16, 0, 0);
    __builtin_amdgcn_global_load_lds((const as1_u32*)(gA + (size_t)64 * K + kt),
                                     (as3_u32*)((char*)lsA + 4096 + lo), 16, 0, 0);
    __builtin_amdgcn_global_load_lds((const as1_u32*)(gB + kt),
                                     (as3_u32*)((char*)lsB + lo), 16, 0, 0);
    __builtin_amdgcn_global_load_lds((const as1_u32*)(gB + (size_t)64 * K + kt),
                                     (as3_u32*)((char*)lsB + 4096 + lo), 16, 0, 0);
    __syncthreads();
    bf16x8 af[4], bfr[4];
#pragma unroll
    for (int mt = 0; mt < 4; ++mt)
      af[mt] = *(const bf16x8*)&lsA[(wr * 64 + mt * 16 + (lane & 15)) * 32 + (lane >> 4) * 8];
#pragma unroll
    for (int nt = 0; nt < 4; ++nt)
      bfr[nt] = *(const bf16x8*)&lsB[(wc * 64 + nt * 16 + (lane & 15)) * 32 + (lane >> 4) * 8];
#pragma unroll
    for (int mt = 0; mt < 4; ++mt)
#pragma unroll
      for (int nt = 0; nt < 4; ++nt)
        acc[mt][nt] = __builtin_amdgcn_mfma_f32_16x16x32_bf16(af[mt], bfr[nt], acc[mt][nt], 0, 0, 0);
    __syncthreads();
  }

#pragma unroll
  for (int mt = 0; mt < 4; ++mt) {
    const int gmb = m0 + wr * 64 + mt * 16 + (lane >> 4) * 4;
#pragma unroll
    for (int nt = 0; nt < 4; ++nt) {
      const int gn = n0 + wc * 64 + nt * 16 + (lane & 15);
#pragma unroll
      for (int r = 0; r < 4; ++r) {
        float v = acc[mt][nt][r];
        if (EPI == 0) {
          outF[(size_t)(gmb + r) * N + gn] = v;
        } else {
          const int row = gmb + r;
          const int b = row >> 11, s = row & (SEQ - 1);
          const int h = gn >> 6, dd = gn & 63;
          if (z < 2) {
            float p = __shfl_xor(v, 1);
            const float2 cs = tab[(s << 5) + (dd >> 1)];
            float o = ((lane & 1) == 0) ? (v * cs.x - p * cs.y) : (p * cs.y + v * cs.x);
            u16* dst = z ? Kh : Qh;
            dst[((size_t)((b * NH + h) * SEQ + s) << 6) + dd] = f2bf(o);
          } else {
            Vt[((size_t)((b * NH + h) << 6) + dd) * SEQ + s] = f2bf(v);
          }
        }
      }
    }
  }
}

// Flash attention, causal. Grid (S/128, B*H), 256 thr. Wave w owns q rows qbase..qbase+31.
__global__ __launch_bounds__(256)
void attn_k(const u16* __restrict__ Qh, const u16* __restrict__ Kh,
            const u16* __restrict__ Vt, u16* __restrict__ AO) {
  __shared__ u16 lsP[4][32 * 72];
  const int t = threadIdx.x, lane = t & 63, w = t >> 6;
  const int bh = blockIdx.y, b = bh >> 4, h = bh & 15;
  const int qbase = blockIdx.x * 128 + w * 32;
  const u16* Qp = Qh + (size_t)bh * SEQ * 64;
  const u16* Kp = Kh + (size_t)bh * SEQ * 64;
  const u16* Vp = Vt + (size_t)bh * 64 * SEQ;

  bf16x8 qa[2][2];
#pragma unroll
  for (int mt = 0; mt < 2; ++mt)
#pragma unroll
    for (int kk = 0; kk < 2; ++kk)
      qa[mt][kk] = *(const bf16x8*)(Qp + (size_t)(qbase + mt * 16 + (lane & 15)) * 64 + kk * 32 + (lane >> 4) * 8);

  f32x4 oacc[2][4] = {};
  float mrun[2][4], lrun[2][4];
#pragma unroll
  for (int mt = 0; mt < 2; ++mt)
#pragma unroll
    for (int r = 0; r < 4; ++r) { mrun[mt][r] = -1e30f; lrun[mt][r] = 0.f; }

  u16* Pw = &lsP[w][0];
  const int tend = (qbase + 31) >> 6;
  for (int kt = 0; kt <= tend; ++kt) {
    const int k0 = kt * 64;
    bf16x8 kb[4][2];
#pragma unroll
    for (int nt = 0; nt < 4; ++nt)
#pragma unroll
      for (int kk = 0; kk < 2; ++kk)
        kb[nt][kk] = *(const bf16x8*)(Kp + (size_t)(k0 + nt * 16 + (lane & 15)) * 64 + kk * 32 + (lane >> 4) * 8);

    f32x4 sc[2][4];
#pragma unroll
    for (int mt = 0; mt < 2; ++mt)
#pragma unroll
      for (int nt = 0; nt < 4; ++nt) {
        f32x4 a = {0.f, 0.f, 0.f, 0.f};
        a = __builtin_amdgcn_mfma_f32_16x16x32_bf16(qa[mt][0], kb[nt][0], a, 0, 0, 0);
        a = __builtin_amdgcn_mfma_f32_16x16x32_bf16(qa[mt][1], kb[nt][1], a, 0, 0, 0);
        sc[mt][nt] = a;
      }

#pragma unroll
    for (int mt = 0; mt < 2; ++mt) {
#pragma unroll
      for (int r = 0; r < 4; ++r) {
        const int qr = qbase + mt * 16 + (lane >> 4) * 4 + r;
        float vmax = -1e30f;
#pragma unroll
        for (int nt = 0; nt < 4; ++nt) {
          const int col = k0 + nt * 16 + (lane & 15);
          float sv = sc[mt][nt][r] * 0.125f;
          sv = (col > qr) ? -1e30f : sv;
          sc[mt][nt][r] = sv;
          vmax = fmaxf(vmax, sv);
        }
#pragma unroll
        for (int off = 1; off < 16; off <<= 1) vmax = fmaxf(vmax, __shfl_xor(vmax, off));
        const float mn = fmaxf(mrun[mt][r], vmax);
        const float al = __expf(mrun[mt][r] - mn);
        mrun[mt][r] = mn;
        float rs = 0.f;
#pragma unroll
        for (int nt = 0; nt < 4; ++nt) {
          float p = __expf(sc[mt][nt][r] - mn);
          sc[mt][nt][r] = p;
          rs += p;
        }
#pragma unroll
        for (int off = 1; off < 16; off <<= 1) rs += __shfl_xor(rs, off);
        lrun[mt][r] = lrun[mt][r] * al + rs;
#pragma unroll
        for (int nt = 0; nt < 4; ++nt) oacc[mt][nt][r] *= al;
      }
    }

    // P (D-frag layout) -> LDS -> A-frag layout
#pragma unroll
    for (int mt = 0; mt < 2; ++mt)
#pragma unroll
      for (int nt = 0; nt < 4; ++nt)
#pragma unroll
        for (int r = 0; r < 4; ++r)
          Pw[(mt * 16 + (lane >> 4) * 4 + r) * 72 + nt * 16 + (lane & 15)] = f2bf(sc[mt][nt][r]);
    asm volatile("s_waitcnt lgkmcnt(0)" ::: "memory");
    __builtin_amdgcn_sched_barrier(0);

    bf16x8 pa[2][2];
#pragma unroll
    for (int mt = 0; mt < 2; ++mt)
#pragma unroll
      for (int kk = 0; kk < 2; ++kk)
        pa[mt][kk] = *(const bf16x8*)&Pw[(mt * 16 + (lane & 15)) * 72 + kk * 32 + (lane >> 4) * 8];

#pragma unroll
    for (int nt = 0; nt < 4; ++nt) {
      const size_t vrow = (size_t)(nt * 16 + (lane & 15)) * SEQ + k0 + (lane >> 4) * 8;
      bf16x8 vb0 = *(const bf16x8*)(Vp + vrow);
      bf16x8 vb1 = *(const bf16x8*)(Vp + vrow + 32);
#pragma unroll
      for (int mt = 0; mt < 2; ++mt) {
        oacc[mt][nt] = __builtin_amdgcn_mfma_f32_16x16x32_bf16(pa[mt][0], vb0, oacc[mt][nt], 0, 0, 0);
        oacc[mt][nt] = __builtin_amdgcn_mfma_f32_16x16x32_bf16(pa[mt][1], vb1, oacc[mt][nt], 0, 0, 0);
      }
    }
  }

#pragma unroll
  for (int mt = 0; mt < 2; ++mt)
#pragma unroll
    for (int r = 0; r < 4; ++r) {
      const int s = qbase + mt * 16 + (lane >> 4) * 4 + r;
      const float inv = 1.f / lrun[mt][r];
#pragma unroll
      for (int nt = 0; nt < 4; ++nt) {
        const int dd = nt * 16 + (lane & 15);
        AO[((size_t)(b * SEQ + s) * NH + h) * 64 + dd] = f2bf(oacc[mt][nt][r] * inv);
      }
    }
}

extern "C" void kernel_launch(void* const* d_in, const int* in_sizes, int n_in,
                              void* d_out, int out_size, void* d_ws, size_t ws_size,
                              hipStream_t stream) {
  const float* x  = (const float*)d_in[0];
  const int*   pos = (const int*)d_in[1];
  const float* Wq = (const float*)d_in[2];
  const float* Wk = (const float*)d_in[3];
  const float* Wv = (const float*)d_in[4];
  const float* Wo = (const float*)d_in[5];
  float* out = (float*)d_out;
  char* ws = (char*)d_ws;
  const size_t MB = 1024 * 1024;
  if (ws_size < 73 * MB) return;  // refuse to scribble OOB

  u16* xb  = (u16*)(ws);             // 16MB; re-used as AO after QKV proj
  u16* wqb = (u16*)(ws + 16 * MB);
  u16* wkb = (u16*)(ws + 18 * MB);
  u16* wvb = (u16*)(ws + 20 * MB);
  u16* wob = (u16*)(ws + 22 * MB);
  u16* Qh  = (u16*)(ws + 24 * MB);
  u16* Kh  = (u16*)(ws + 40 * MB);
  u16* Vt  = (u16*)(ws + 56 * MB);
  float2* tab = (float2*)(ws + 72 * MB);
  u16* AO = xb;

  cast_bf16_k<<<(MTOT * DM / 4) / 256, 256, 0, stream>>>(x, xb, MTOT * DM / 4);
  cast_bf16_k<<<(DM * DM / 4) / 256, 256, 0, stream>>>(Wq, wqb, DM * DM / 4);
  cast_bf16_k<<<(DM * DM / 4) / 256, 256, 0, stream>>>(Wk, wkb, DM * DM / 4);
  cast_bf16_k<<<(DM * DM / 4) / 256, 256, 0, stream>>>(Wv, wvb, DM * DM / 4);
  cast_bf16_k<<<(DM * DM / 4) / 256, 256, 0, stream>>>(Wo, wob, DM * DM / 4);
  rope_tab_k<<<(SEQ * 32) / 256, 256, 0, stream>>>(pos, tab);

  gemm_bt<1><<<dim3(8, 64, 3), 256, 0, stream>>>(xb, wqb, wkb, wvb, nullptr, Qh, Kh, Vt, tab);
  attn_k<<<dim3(16, 64), 256, 0, stream>>>(Qh, Kh, Vt, AO);
  gemm_bt<0><<<dim3(8, 64, 1), 256, 0, stream>>>(AO, wob, wob, wob, out, nullptr, nullptr, nullptr, nullptr);
}

// Round 2
// 282.147 us; speedup vs baseline: 1.4456x; 1.4456x over previous
//
#include <hip/hip_runtime.h>

#define SEQ   2048
#define BATCH 4
#define NH    16
#define DM    1024
#define MTOT  (BATCH*SEQ)   // 8192

typedef unsigned short u16;
typedef unsigned int   u32;
typedef __attribute__((ext_vector_type(8))) __bf16 bf16x8;
typedef __attribute__((ext_vector_type(4))) float  f32x4;
typedef __attribute__((address_space(1))) u32 as1_u32;
typedef __attribute__((address_space(3))) u32 as3_u32;

__device__ __forceinline__ u16 f2bf(float f) {
  union { float f; u32 u; } c; c.f = f;
  return (u16)((c.u + 0x7fffu + ((c.u >> 16) & 1u)) >> 16);
}

__global__ void cast_bf16_k(const float* __restrict__ in, u16* __restrict__ out, int n4) {
  int i = blockIdx.x * blockDim.x + threadIdx.x;
  if (i < n4) {
    float4 v = reinterpret_cast<const float4*>(in)[i];
    ushort4 o;
    o.x = f2bf(v.x); o.y = f2bf(v.y); o.z = f2bf(v.z); o.w = f2bf(v.w);
    reinterpret_cast<ushort4*>(out)[i] = o;
  }
}

__global__ void rope_tab_k(const int* __restrict__ pos, float2* __restrict__ tab) {
  int i = blockIdx.x * blockDim.x + threadIdx.x;  // s*32 + j
  if (i < SEQ * 32) {
    int s = i >> 5, j = i & 31;
    float p = (float)pos[s];
    float fr = powf(10000.f, -(float)j / 32.f);
    float a = p * fr;
    tab[i] = make_float2(cosf(a), sinf(a));
  }
}

// C = A @ Bt^T.  A: [M,1024] bf16 row-major. Bt: [1024,1024] bf16 row-major ([N][K]).
// EPI 0: fp32 store to outF. EPI 1: z=0/1 -> RoPE -> Qh/Kh [B,H,S,64]; z=2 -> Vt [B,H,64,S].
// Q additionally scaled by 0.125*log2(e) so attention can use exp2 with no extra mult.
template<int EPI>
__global__ __launch_bounds__(256)
void gemm_bt(const u16* __restrict__ A,
             const u16* __restrict__ B0, const u16* __restrict__ B1, const u16* __restrict__ B2,
             float* __restrict__ outF,
             u16* __restrict__ Qh, u16* __restrict__ Kh, u16* __restrict__ Vt,
             const float2* __restrict__ tab) {
  const int K = DM, N = DM;
  __shared__ u16 lsA[128 * 32];
  __shared__ u16 lsB[128 * 32];
  const int t = threadIdx.x;
  const int lane = t & 63;
  const int wid = t >> 6;
  const int wr = wid >> 1, wc = wid & 1;
  const int m0 = blockIdx.y * 128, n0 = blockIdx.x * 128;
  const int z = blockIdx.z;
  const u16* Bt = (z == 0) ? B0 : (z == 1 ? B1 : B2);

  f32x4 acc[4][4] = {};

  const int srow = t >> 2;
  const int scol = (t & 3) * 8;
  const u16* gA = A + (size_t)(m0 + srow) * K + scol;
  const u16* gB = Bt + (size_t)(n0 + srow) * K + scol;
  const u32 lo = (u32)t * 16u;

  for (int kt = 0; kt < K; kt += 32) {
    __builtin_amdgcn_global_load_lds((const as1_u32*)(gA + kt),
                                     (as3_u32*)((char*)lsA + lo), 16, 0, 0);
    __builtin_amdgcn_global_load_lds((const as1_u32*)(gA + (size_t)64 * K + kt),
                                     (as3_u32*)((char*)lsA + 4096 + lo), 16, 0, 0);
    __builtin_amdgcn_global_load_lds((const as1_u32*)(gB + kt),
                                     (as3_u32*)((char*)lsB + lo), 16, 0, 0);
    __builtin_amdgcn_global_load_lds((const as1_u32*)(gB + (size_t)64 * K + kt),
                                     (as3_u32*)((char*)lsB + 4096 + lo), 16, 0, 0);
    __syncthreads();
    bf16x8 af[4], bfr[4];
#pragma unroll
    for (int mt = 0; mt < 4; ++mt)
      af[mt] = *(const bf16x8*)&lsA[(wr * 64 + mt * 16 + (lane & 15)) * 32 + (lane >> 4) * 8];
#pragma unroll
    for (int nt = 0; nt < 4; ++nt)
      bfr[nt] = *(const bf16x8*)&lsB[(wc * 64 + nt * 16 + (lane & 15)) * 32 + (lane >> 4) * 8];
#pragma unroll
    for (int mt = 0; mt < 4; ++mt)
#pragma unroll
      for (int nt = 0; nt < 4; ++nt)
        acc[mt][nt] = __builtin_amdgcn_mfma_f32_16x16x32_bf16(af[mt], bfr[nt], acc[mt][nt], 0, 0, 0);
    __syncthreads();
  }

#pragma unroll
  for (int mt = 0; mt < 4; ++mt) {
    const int gmb = m0 + wr * 64 + mt * 16 + (lane >> 4) * 4;
#pragma unroll
    for (int nt = 0; nt < 4; ++nt) {
      const int gn = n0 + wc * 64 + nt * 16 + (lane & 15);
#pragma unroll
      for (int r = 0; r < 4; ++r) {
        float v = acc[mt][nt][r];
        if (EPI == 0) {
          outF[(size_t)(gmb + r) * N + gn] = v;
        } else {
          const int row = gmb + r;
          const int b = row >> 11, s = row & (SEQ - 1);
          const int h = gn >> 6, dd = gn & 63;
          if (z < 2) {
            float p = __shfl_xor(v, 1);
            const float2 cs = tab[(s << 5) + (dd >> 1)];
            float o = ((lane & 1) == 0) ? (v * cs.x - p * cs.y) : (p * cs.y + v * cs.x);
            if (z == 0) o *= 0.18033688011112042f;  // 0.125 * log2(e)
            u16* dst = z ? Kh : Qh;
            dst[((size_t)((b * NH + h) * SEQ + s) << 6) + dd] = f2bf(o);
          } else {
            Vt[((size_t)((b * NH + h) << 6) + dd) * SEQ + s] = f2bf(v);
          }
        }
      }
    }
  }
}

// Flash attention, causal, scores pre-scaled into log2 domain (exp2 softmax).
// Grid (8, B*H), 256 thr, 4 independent waves/block. Wave gw = bx*4+w handles
// two 32-row q-chunks sequentially: gw and 63-gw -> ~constant work per wave.
__global__ __launch_bounds__(256)
void attn_k(const u16* __restrict__ Qh, const u16* __restrict__ Kh,
            const u16* __restrict__ Vt, u16* __restrict__ AO) {
  __shared__ u16 lsP[4][32 * 72];
  const int t = threadIdx.x, lane = t & 63, w = t >> 6;
  const int bh = blockIdx.y, b = bh >> 4, h = bh & 15;
  const int gw = blockIdx.x * 4 + w;  // [0,32)
  const u16* Qp = Qh + (size_t)bh * SEQ * 64;
  const u16* Kp = Kh + (size_t)bh * SEQ * 64;
  const u16* Vp = Vt + (size_t)bh * 64 * SEQ;
  u16* Pw = &lsP[w][0];

  for (int ph = 0; ph < 2; ++ph) {
    const int qc = ph ? (63 - gw) : gw;
    const int qbase = qc * 32;
    const int tend = (qbase + 31) >> 6;

    bf16x8 qa[2][2];
#pragma unroll
    for (int mt = 0; mt < 2; ++mt)
#pragma unroll
      for (int kk = 0; kk < 2; ++kk)
        qa[mt][kk] = *(const bf16x8*)(Qp + (size_t)(qbase + mt * 16 + (lane & 15)) * 64 + kk * 32 + (lane >> 4) * 8);

    f32x4 oacc[2][4] = {};
    float mrun[2][4], lrun[2][4];
#pragma unroll
    for (int mt = 0; mt < 2; ++mt)
#pragma unroll
      for (int r = 0; r < 4; ++r) { mrun[mt][r] = -1e30f; lrun[mt][r] = 0.f; }

    // prefetch K tile 0
    bf16x8 kb[4][2];
#pragma unroll
    for (int nt = 0; nt < 4; ++nt)
#pragma unroll
      for (int kk = 0; kk < 2; ++kk)
        kb[nt][kk] = *(const bf16x8*)(Kp + (size_t)(nt * 16 + (lane & 15)) * 64 + kk * 32 + (lane >> 4) * 8);

    for (int kt = 0; kt <= tend; ++kt) {
      const int k0 = kt * 64;

      // issue V loads early -- they fly during QK + softmax
      bf16x8 vb[4][2];
#pragma unroll
      for (int nt = 0; nt < 4; ++nt) {
        const size_t vrow = (size_t)(nt * 16 + (lane & 15)) * SEQ + k0 + (lane >> 4) * 8;
        vb[nt][0] = *(const bf16x8*)(Vp + vrow);
        vb[nt][1] = *(const bf16x8*)(Vp + vrow + 32);
      }

      f32x4 sc[2][4];
#pragma unroll
      for (int mt = 0; mt < 2; ++mt)
#pragma unroll
        for (int nt = 0; nt < 4; ++nt) {
          f32x4 a = {0.f, 0.f, 0.f, 0.f};
          a = __builtin_amdgcn_mfma_f32_16x16x32_bf16(qa[mt][0], kb[nt][0], a, 0, 0, 0);
          a = __builtin_amdgcn_mfma_f32_16x16x32_bf16(qa[mt][1], kb[nt][1], a, 0, 0, 0);
          sc[mt][nt] = a;
        }

      // prefetch next K tile while softmax runs (kb regs are dead after QK mfmas)
      if (kt < tend) {
        const int kn = k0 + 64;
#pragma unroll
        for (int nt = 0; nt < 4; ++nt)
#pragma unroll
          for (int kk = 0; kk < 2; ++kk)
            kb[nt][kk] = *(const bf16x8*)(Kp + (size_t)(kn + nt * 16 + (lane & 15)) * 64 + kk * 32 + (lane >> 4) * 8);
      }

      const bool diag = (kt == tend);
#pragma unroll
      for (int mt = 0; mt < 2; ++mt) {
#pragma unroll
        for (int r = 0; r < 4; ++r) {
          const int qr = qbase + mt * 16 + (lane >> 4) * 4 + r;
          float vmax = -1e30f;
          if (diag) {
#pragma unroll
            for (int nt = 0; nt < 4; ++nt) {
              const int col = k0 + nt * 16 + (lane & 15);
              float sv = (col > qr) ? -1e30f : sc[mt][nt][r];
              sc[mt][nt][r] = sv;
              vmax = fmaxf(vmax, sv);
            }
          } else {
#pragma unroll
            for (int nt = 0; nt < 4; ++nt) vmax = fmaxf(vmax, sc[mt][nt][r]);
          }
#pragma unroll
          for (int off = 1; off < 16; off <<= 1) vmax = fmaxf(vmax, __shfl_xor(vmax, off));
          const float mn = fmaxf(mrun[mt][r], vmax);
          const float al = exp2f(mrun[mt][r] - mn);
          mrun[mt][r] = mn;
          float rs = 0.f;
#pragma unroll
          for (int nt = 0; nt < 4; ++nt) {
            float p = exp2f(sc[mt][nt][r] - mn);
            sc[mt][nt][r] = p;
            rs += p;
          }
#pragma unroll
          for (int off = 1; off < 16; off <<= 1) rs += __shfl_xor(rs, off);
          lrun[mt][r] = lrun[mt][r] * al + rs;
#pragma unroll
          for (int nt = 0; nt < 4; ++nt) oacc[mt][nt][r] *= al;
        }
      }

      // P (D-frag layout) -> LDS -> A-frag layout
#pragma unroll
      for (int mt = 0; mt < 2; ++mt)
#pragma unroll
        for (int nt = 0; nt < 4; ++nt)
#pragma unroll
          for (int r = 0; r < 4; ++r)
            Pw[(mt * 16 + (lane >> 4) * 4 + r) * 72 + nt * 16 + (lane & 15)] = f2bf(sc[mt][nt][r]);
      asm volatile("s_waitcnt lgkmcnt(0)" ::: "memory");
      __builtin_amdgcn_sched_barrier(0);

      bf16x8 pa[2][2];
#pragma unroll
      for (int mt = 0; mt < 2; ++mt)
#pragma unroll
        for (int kk = 0; kk < 2; ++kk)
          pa[mt][kk] = *(const bf16x8*)&Pw[(mt * 16 + (lane & 15)) * 72 + kk * 32 + (lane >> 4) * 8];
      __builtin_amdgcn_sched_barrier(0);

#pragma unroll
      for (int nt = 0; nt < 4; ++nt)
#pragma unroll
        for (int mt = 0; mt < 2; ++mt) {
          oacc[mt][nt] = __builtin_amdgcn_mfma_f32_16x16x32_bf16(pa[mt][0], vb[nt][0], oacc[mt][nt], 0, 0, 0);
          oacc[mt][nt] = __builtin_amdgcn_mfma_f32_16x16x32_bf16(pa[mt][1], vb[nt][1], oacc[mt][nt], 0, 0, 0);
        }
    }

#pragma unroll
    for (int mt = 0; mt < 2; ++mt)
#pragma unroll
      for (int r = 0; r < 4; ++r) {
        const int s = qbase + mt * 16 + (lane >> 4) * 4 + r;
        const float inv = 1.f / lrun[mt][r];
#pragma unroll
        for (int nt = 0; nt < 4; ++nt) {
          const int dd = nt * 16 + (lane & 15);
          AO[((size_t)(b * SEQ + s) * NH + h) * 64 + dd] = f2bf(oacc[mt][nt][r] * inv);
        }
      }
  }
}

extern "C" void kernel_launch(void* const* d_in, const int* in_sizes, int n_in,
                              void* d_out, int out_size, void* d_ws, size_t ws_size,
                              hipStream_t stream) {
  const float* x  = (const float*)d_in[0];
  const int*   pos = (const int*)d_in[1];
  const float* Wq = (const float*)d_in[2];
  const float* Wk = (const float*)d_in[3];
  const float* Wv = (const float*)d_in[4];
  const float* Wo = (const float*)d_in[5];
  float* out = (float*)d_out;
  char* ws = (char*)d_ws;
  const size_t MB = 1024 * 1024;
  if (ws_size < 73 * MB) return;  // refuse to scribble OOB

  u16* xb  = (u16*)(ws);             // 16MB; re-used as AO after QKV proj
  u16* wqb = (u16*)(ws + 16 * MB);
  u16* wkb = (u16*)(ws + 18 * MB);
  u16* wvb = (u16*)(ws + 20 * MB);
  u16* wob = (u16*)(ws + 22 * MB);
  u16* Qh  = (u16*)(ws + 24 * MB);
  u16* Kh  = (u16*)(ws + 40 * MB);
  u16* Vt  = (u16*)(ws + 56 * MB);
  float2* tab = (float2*)(ws + 72 * MB);
  u16* AO = xb;

  cast_bf16_k<<<(MTOT * DM / 4) / 256, 256, 0, stream>>>(x, xb, MTOT * DM / 4);
  cast_bf16_k<<<(DM * DM / 4) / 256, 256, 0, stream>>>(Wq, wqb, DM * DM / 4);
  cast_bf16_k<<<(DM * DM / 4) / 256, 256, 0, stream>>>(Wk, wkb, DM * DM / 4);
  cast_bf16_k<<<(DM * DM / 4) / 256, 256, 0, stream>>>(Wv, wvb, DM * DM / 4);
  cast_bf16_k<<<(DM * DM / 4) / 256, 256, 0, stream>>>(Wo, wob, DM * DM / 4);
  rope_tab_k<<<(SEQ * 32) / 256, 256, 0, stream>>>(pos, tab);

  gemm_bt<1><<<dim3(8, 64, 3), 256, 0, stream>>>(xb, wqb, wkb, wvb, nullptr, Qh, Kh, Vt, tab);
  attn_k<<<dim3(8, 64), 256, 0, stream>>>(Qh, Kh, Vt, AO);
  gemm_bt<0><<<dim3(8, 64, 1), 256, 0, stream>>>(AO, wob, wob, wob, out, nullptr, nullptr, nullptr, nullptr);
}